// Round 2
// baseline (242.359 us; speedup 1.0000x reference)
//
#include <hip/hip_runtime.h>
#include <math.h>

// GPR_58746562675312: haversine-windowed weighted mean.
//   m[y] = sum_x w(y,x)*x[x] / sum_x w(y,x),  w = d if d<0.25 else 0,
//   d = 12.756 * asin(sqrt(hav(y,x)));  out = [m (ny), 0.001 (ny)]
//
// Numerics: the harness's reference is the numpy FP32 chain. Far from the
// threshold the fast fp32 poly path decides correctly; within +-3e-4 of
// d=0.25 we re-evaluate with a step-by-step emulation of the fp32 chain:
// each arithmetic op correctly-rounded fp32 (no FMA), each transcendental
// computed in fp64 then rounded to fp32 (= correctly-rounded fp32 sin/cos/
// asin/sqrt). Matches any faithful (<=1ulp) fp32 implementation on ~all args.

#define YPB   4     // y rows per block == waves per block
#define TPB   256
#define TILE  256

__global__ __launch_bounds__(TPB) void gpr_kernel(
    const float* __restrict__ x,    // [nx]
    const float* __restrict__ x_l,  // [nx,2] (lon, lat) degrees
    const float* __restrict__ y_l,  // [ny,2]
    float* __restrict__ out,        // [2*ny]
    int nx, int ny)
{
    __shared__ float4 tile[TILE];

    const int tid  = threadIdx.x;
    const int wave = tid >> 6;
    const int lane = tid & 63;
    const int y    = blockIdx.x * YPB + wave;

    const float d2r    = 0.017453292519943295f;  // fl32(pi/180) = 0x3C8EFA35
    const float THRESH = 0.25f;
    const float DIAM   = 12.756f;                // fl32(2*6.378)

    // sin(a) ~= a*(1 + t*(c3 + t*c5)), t=a^2   (|a|<=0.175: err ~1e-9)
    const float c3 = -0.16666667f;
    const float c5 =  0.00833333333f;
    // asin(r) ~= r*(1 + t*(a3 + t*a5)), t=r^2  (r<=0.25: err ~1e-5, but
    // near the cut r~0.0196 err ~2e-10)
    const float a3 = 0.16666667f;
    const float a5 = 0.075f;

    float lon_y = 0.0f, lat_y = 0.0f;
    if (y < ny) { lon_y = y_l[2 * y]; lat_y = y_l[2 * y + 1]; }
    const float cly = cosf(lat_y * d2r);

    float accw = 0.0f, accwx = 0.0f;

    const int ntiles = (nx + TILE - 1) / TILE;
    for (int t = 0; t < ntiles; ++t) {
        const int base = t * TILE;
        __syncthreads();   // previous tile fully consumed
        {
            const int i = base + tid;
            if (i < nx) {
                float lon = x_l[2 * i];
                float lat = x_l[2 * i + 1];
                float xv  = x[i];
                // cos(a) ~= 1 + t*(-1/2 + t*(1/24 - t/720)), t=a^2 (err ~2e-11)
                float a  = lat * d2r;
                float tt = a * a;
                float cl = fmaf(tt, fmaf(tt, fmaf(tt, -1.3888889e-3f,
                                                      4.1666668e-2f), -0.5f), 1.0f);
                tile[tid] = make_float4(lon, lat, cl, xv);
            }
        }
        __syncthreads();

        const int tn = min(TILE, nx - base);
        for (int k = lane; k < tn; k += 64) {
            float4 e = tile[k];   // (lon_x, lat_x, cos(lat_x*d2r), xval)

            float a1 = (e.y - lat_y) * d2r;
            float t1 = a1 * a1;
            float sl = a1 * fmaf(t1, fmaf(t1, c5, c3), 1.0f);

            float a2 = (e.x - lon_y) * d2r;
            float t2 = a2 * a2;
            float sd = a2 * fmaf(t2, fmaf(t2, c5, c3), 1.0f);

            float cxy = e.z * cly;
            float hav = fmaf(cxy * sd, sd, sl * sl);

            float r  = sqrtf(hav);
            float rr = r * r;
            float d  = (r * fmaf(rr, fmaf(rr, a5, a3), 1.0f)) * DIAM;

            float w;
            if (__builtin_expect(fabsf(d - THRESH) < 3e-4f, 0)) {
                // Emulate the numpy fp32 chain, every step correctly rounded.
                float dlat = __fsub_rn(e.y, lat_y);
                float alat = __fmul_rn(dlat, d2r);
                float slf  = (float)sin((double)alat);        // CR fp32 sin
                float h1   = __fmul_rn(slf, slf);

                float axl  = __fmul_rn(e.y,  d2r);
                float ayl  = __fmul_rn(lat_y, d2r);
                float cxf  = (float)cos((double)axl);         // CR fp32 cos
                float cyf  = (float)cos((double)ayl);
                float cc   = __fmul_rn(cxf, cyf);

                float dlon = __fsub_rn(e.x, lon_y);
                float alon = __fmul_rn(dlon, d2r);
                float sdf  = (float)sin((double)alon);
                float h2   = __fmul_rn(sdf, sdf);

                float hv   = __fadd_rn(h1, __fmul_rn(cc, h2));
                float r32  = (float)sqrt((double)hv);         // CR fp32 sqrt
                float as32 = (float)asin((double)r32);        // CR fp32 asin
                float dnp  = __fmul_rn(DIAM, as32);
                w = (dnp < THRESH) ? dnp : 0.0f;
            } else {
                w = (d < THRESH) ? d : 0.0f;
            }

            accw  += w;
            accwx  = fmaf(w, e.w, accwx);
        }
    }

    // wave-level butterfly reduction (64 lanes)
    #pragma unroll
    for (int off = 32; off > 0; off >>= 1) {
        accw  += __shfl_xor(accw,  off, 64);
        accwx += __shfl_xor(accwx, off, 64);
    }

    if (lane == 0 && y < ny) {
        float m = (accw > 0.0f) ? (accwx / fmaxf(accw, 1e-12f)) : 0.0f;
        out[y]      = m;
        out[ny + y] = 0.001f;
    }
}

extern "C" void kernel_launch(void* const* d_in, const int* in_sizes, int n_in,
                              void* d_out, int out_size, void* d_ws, size_t ws_size,
                              hipStream_t stream) {
    const float* x   = (const float*)d_in[0];
    const float* x_l = (const float*)d_in[1];
    const float* y_l = (const float*)d_in[2];
    float* out = (float*)d_out;

    const int nx = in_sizes[0];        // 20000
    const int ny = in_sizes[2] / 2;    // 6000

    const int blocks = (ny + YPB - 1) / YPB;
    gpr_kernel<<<blocks, TPB, 0, stream>>>(x, x_l, y_l, out, nx, ny);
}

// Round 3
// 168.317 us; speedup vs baseline: 1.4399x; 1.4399x over previous
//
#include <hip/hip_runtime.h>
#include <math.h>

// GPR_58746562675312: haversine-windowed weighted mean.
//   m[y] = sum_x w(y,x)*x[x] / sum_x w(y,x),  w = d if d<0.25 else 0,
//   d = 12.756 * asin(sqrt(hav(y,x)));  out = [m (ny), 0.001 (ny)]
//
// R3 structure:
//  - pre_kernel: per-x (sin lat, cos lat, sin lon, cos lon) + x value -> d_ws
//    (sin(a-b)=sa*cb-ca*sb collapses per-pair trig from 10 VALU to 4).
//  - Decision moved to hav space: d<0.25 <=> hav < Hcut=sin^2(0.25/12.756).
//    Band on hav of +-5e-8 (=+-1.6e-5 in d, 25x margin over the ~2e-9
//    decision-variable discrepancy vs numpy's fp32 chain) -> fp64 CR
//    emulation now hits ~1.5k pairs instead of ~29k.
//  - Raw v_sqrt + 2-instr poly for d magnitude (only needs ~1e-4 rel).
//  - Band path emulates the numpy fp32 chain step-by-step, correctly
//    rounded (byte-identical to the round-2 code that passed).

#define YPB   4     // y rows per block == waves per block
#define TPB   256
#define TILE  1024

__device__ __forceinline__ float sin_poly(float a) {
    float t = a * a;   // |a| <= 0.1746: err ~1e-9
    return a * fmaf(t, fmaf(t, 8.3333333e-3f, -0.16666667f), 1.0f);
}
__device__ __forceinline__ float cos_poly(float a) {
    float t = a * a;   // err ~2e-11
    return fmaf(t, fmaf(t, fmaf(t, -1.3888889e-3f, 4.1666668e-2f), -0.5f), 1.0f);
}

__global__ __launch_bounds__(TPB) void pre_kernel(
    const float* __restrict__ x, const float* __restrict__ x_l,
    float4* __restrict__ wsA, float* __restrict__ wsX, int nx)
{
    const float d2r = 0.017453292519943295f;
    int i = blockIdx.x * TPB + threadIdx.x;
    if (i < nx) {
        float lon = x_l[2 * i];
        float lat = x_l[2 * i + 1];
        float al = lat * d2r, ao = lon * d2r;
        wsA[i] = make_float4(sin_poly(al), cos_poly(al), sin_poly(ao), cos_poly(ao));
        wsX[i] = x[i];
    }
}

__global__ __launch_bounds__(TPB) void gpr_kernel(
    const float* __restrict__ x,    // [nx] (band path + fallback)
    const float* __restrict__ x_l,  // [nx,2] raw degrees (band path + fallback)
    const float4* __restrict__ wsA, // [nx] (slat, clat, slon, clon)
    const float* __restrict__ wsX,  // [nx] x values
    const float* __restrict__ y_l,  // [ny,2]
    float* __restrict__ out,        // [2*ny]
    int nx, int ny, float Hcut, int use_ws)
{
    __shared__ float4 tA[TILE];
    __shared__ float  tX[TILE];

    const int tid  = threadIdx.x;
    const int wave = tid >> 6;
    const int lane = tid & 63;
    const int y    = blockIdx.x * YPB + wave;

    const float d2r    = 0.017453292519943295f;  // fl32(pi/180)
    const float THRESH = 0.25f;
    const float DIAM   = 12.756f;
    const float DIAM6  = 12.756f / 6.0f;
    const float EPS_H  = 5e-8f;

    float lon_y = 0.0f, lat_y = 0.0f;
    if (y < ny) { lon_y = y_l[2 * y]; lat_y = y_l[2 * y + 1]; }
    const float sly   = sin_poly(lat_y * d2r);
    const float cly   = cos_poly(lat_y * d2r);
    const float slony = sin_poly(lon_y * d2r);
    const float clony = cos_poly(lon_y * d2r);

    float accw = 0.0f, accwx = 0.0f;

    const int ntiles = (nx + TILE - 1) / TILE;
    for (int t = 0; t < ntiles; ++t) {
        const int base = t * TILE;
        __syncthreads();   // previous tile fully consumed
        if (use_ws) {
            #pragma unroll
            for (int j = 0; j < TILE / TPB; ++j) {
                int idx = j * TPB + tid, i = base + idx;
                if (i < nx) { tA[idx] = wsA[i]; tX[idx] = wsX[i]; }
            }
        } else {
            #pragma unroll
            for (int j = 0; j < TILE / TPB; ++j) {
                int idx = j * TPB + tid, i = base + idx;
                if (i < nx) {
                    float lon = x_l[2 * i], lat = x_l[2 * i + 1];
                    tA[idx] = make_float4(sin_poly(lat * d2r), cos_poly(lat * d2r),
                                          sin_poly(lon * d2r), cos_poly(lon * d2r));
                    tX[idx] = x[i];
                }
            }
        }
        __syncthreads();

        const int tn = min(TILE, nx - base);

        auto body = [&](int k) {
            float4 e  = tA[k];   // (slat_x, clat_x, slon_x, clon_x)
            float  xv = tX[k];

            float sl  = fmaf(e.x, cly,   -(e.y * sly));    // sin(dlat*d2r)
            float sd  = fmaf(e.z, clony, -(e.w * slony));  // sin(dlon*d2r)
            float cxy = e.y * cly;
            float hav = fmaf(sl, sl, cxy * (sd * sd));

            float tb  = hav - Hcut;
            float r   = __builtin_amdgcn_sqrtf(hav);
            float d   = r * fmaf(hav, DIAM6, DIAM);

            float w;
            if (__builtin_expect(fabsf(tb) < EPS_H, 0)) {
                // Emulate the numpy fp32 chain, every step correctly rounded.
                // (byte-identical to round-2 band path, raw coords refetched)
                int   i    = base + k;
                float lonx = x_l[2 * i], latx = x_l[2 * i + 1];

                float dlat = __fsub_rn(latx, lat_y);
                float alat = __fmul_rn(dlat, d2r);
                float slf  = (float)sin((double)alat);        // CR fp32 sin
                float h1   = __fmul_rn(slf, slf);

                float axl  = __fmul_rn(latx,  d2r);
                float ayl  = __fmul_rn(lat_y, d2r);
                float cxf  = (float)cos((double)axl);         // CR fp32 cos
                float cyf  = (float)cos((double)ayl);
                float cc   = __fmul_rn(cxf, cyf);

                float dlon = __fsub_rn(lonx, lon_y);
                float alon = __fmul_rn(dlon, d2r);
                float sdf  = (float)sin((double)alon);
                float h2   = __fmul_rn(sdf, sdf);

                float hv   = __fadd_rn(h1, __fmul_rn(cc, h2));
                float r32  = (float)sqrt((double)hv);         // CR fp32 sqrt
                float as32 = (float)asin((double)r32);        // CR fp32 asin
                float dnp  = __fmul_rn(DIAM, as32);
                w = (dnp < THRESH) ? dnp : 0.0f;
            } else {
                w = (tb < 0.0f) ? d : 0.0f;
            }

            accw += w;
            accwx = fmaf(w, xv, accwx);
        };

        if (tn == TILE) {
            #pragma unroll 4
            for (int k0 = 0; k0 < TILE / 64; ++k0) body(k0 * 64 + lane);
        } else {
            for (int k = lane; k < tn; k += 64) body(k);
        }
    }

    // wave-level butterfly reduction (64 lanes)
    #pragma unroll
    for (int off = 32; off > 0; off >>= 1) {
        accw  += __shfl_xor(accw,  off, 64);
        accwx += __shfl_xor(accwx, off, 64);
    }

    if (lane == 0 && y < ny) {
        float m = (accw > 0.0f) ? (accwx / fmaxf(accw, 1e-12f)) : 0.0f;
        out[y]      = m;
        out[ny + y] = 0.001f;
    }
}

extern "C" void kernel_launch(void* const* d_in, const int* in_sizes, int n_in,
                              void* d_out, int out_size, void* d_ws, size_t ws_size,
                              hipStream_t stream) {
    const float* x   = (const float*)d_in[0];
    const float* x_l = (const float*)d_in[1];
    const float* y_l = (const float*)d_in[2];
    float* out = (float*)d_out;

    const int nx = in_sizes[0];        // 20000
    const int ny = in_sizes[2] / 2;    // 6000

    // hav threshold, computed in fp64 on host: sin^2(0.25/12.756)
    double th = 0.25 / 12.756;
    double s  = sin(th);
    float Hcut = (float)(s * s);

    float4* wsA = (float4*)d_ws;
    float*  wsX = (float*)((char*)d_ws + (size_t)nx * 16);
    int use_ws = (ws_size >= (size_t)nx * 20) ? 1 : 0;

    if (use_ws) {
        int pb = (nx + TPB - 1) / TPB;
        pre_kernel<<<pb, TPB, 0, stream>>>(x, x_l, wsA, wsX, nx);
    }
    const int blocks = (ny + YPB - 1) / YPB;
    gpr_kernel<<<blocks, TPB, 0, stream>>>(x, x_l, wsA, wsX, y_l, out,
                                           nx, ny, Hcut, use_ws);
}

// Round 4
// 93.733 us; speedup vs baseline: 2.5856x; 1.7957x over previous
//
#include <hip/hip_runtime.h>
#include <math.h>

// GPR_58746562675312: haversine-windowed weighted mean.
//   m[y] = sum_x w(y,x)*x[x] / sum_x w(y,x),  w = d if d<0.25 else 0,
//   d = 12.756 * asin(sqrt(hav(y,x)));  out = [m (ny), 0.001 (ny)]
//
// R4: spatial binning. Cutoff radius is 1.123 deg (reference uses sin(D),
// not sin(D/2)) in a 10x10 deg region -> only ~4% of pairs contribute.
// Counting-sort x into a 40x40 grid (0.25 deg cells) in d_ws, then each
// y-wave scans only the contiguous per-strip segments whose cells can
// intersect the disk (conservative windows, +4e-3 deg margins >> 1e-6
// numpy-chain wobble). ~19x less inner-loop work than full scan.
// Boundary decisions: band +-5e-8 on hav -> CR fp32-chain emulation
// (byte-identical to the R2/R3 path that passed).

#define TPB    256
#define YPB    4      // y rows per block == waves per block (main kernel)
#define NSTRIP 40
#define NLON   40
#define NCELLS (NSTRIP * NLON)
#define C_CELL   0.25f
#define INV_CELL 4.0f
#define RLAT     1.1250f   // conservative window radius in degrees

__device__ __forceinline__ float sin_poly(float a) {
    float t = a * a;   // |a| <= 0.1746: err ~1e-9
    return a * fmaf(t, fmaf(t, 8.3333333e-3f, -0.16666667f), 1.0f);
}
__device__ __forceinline__ float cos_poly(float a) {
    float t = a * a;   // err ~2e-11
    return fmaf(t, fmaf(t, fmaf(t, -1.3888889e-3f, 4.1666668e-2f), -0.5f), 1.0f);
}
__device__ __forceinline__ int cell_of(float lon, float lat) {
    int s = (int)(lat * INV_CELL); s = min(max(s, 0), NSTRIP - 1);
    int l = (int)(lon * INV_CELL); l = min(max(l, 0), NLON - 1);
    return s * NLON + l;
}

// ---- binning pipeline -------------------------------------------------

__global__ __launch_bounds__(TPB) void zero_kernel(int* __restrict__ hist) {
    for (int i = threadIdx.x; i < NCELLS; i += TPB) hist[i] = 0;
}

__global__ __launch_bounds__(TPB) void hist_kernel(
    const float* __restrict__ x_l, int* __restrict__ hist, int nx)
{
    int i = blockIdx.x * TPB + threadIdx.x;
    if (i < nx) atomicAdd(&hist[cell_of(x_l[2 * i], x_l[2 * i + 1])], 1);
}

// single block: exclusive scan of hist[NCELLS] -> cellStart (+total at end),
// and initialize cursor = cellStart.
__global__ __launch_bounds__(TPB) void scan_kernel(
    const int* __restrict__ hist, int* __restrict__ cellStart,
    int* __restrict__ cursor)
{
    const int CHUNK = (NCELLS + TPB - 1) / TPB;   // 7
    __shared__ int sums[TPB];
    int tid = threadIdx.x;
    int base = tid * CHUNK;
    int local[7];
    int s = 0;
    #pragma unroll
    for (int j = 0; j < CHUNK; ++j) {
        int idx = base + j;
        int v = (idx < NCELLS) ? hist[idx] : 0;
        local[j] = s; s += v;
    }
    sums[tid] = s;
    __syncthreads();
    for (int off = 1; off < TPB; off <<= 1) {
        int t = (tid >= off) ? sums[tid - off] : 0;
        __syncthreads();
        sums[tid] += t;
        __syncthreads();
    }
    int excl = (tid > 0) ? sums[tid - 1] : 0;
    #pragma unroll
    for (int j = 0; j < CHUNK; ++j) {
        int idx = base + j;
        if (idx < NCELLS) { cellStart[idx] = excl + local[j]; cursor[idx] = excl + local[j]; }
    }
    if (tid == TPB - 1) cellStart[NCELLS] = sums[TPB - 1];
}

__global__ __launch_bounds__(TPB) void scatter_kernel(
    const float* __restrict__ x, const float* __restrict__ x_l,
    int* __restrict__ cursor, float4* __restrict__ sortedA,
    float2* __restrict__ sortedRaw, float* __restrict__ sortedX, int nx)
{
    const float d2r = 0.017453292519943295f;
    int i = blockIdx.x * TPB + threadIdx.x;
    if (i < nx) {
        float lon = x_l[2 * i], lat = x_l[2 * i + 1];
        int pos = atomicAdd(&cursor[cell_of(lon, lat)], 1);
        float al = lat * d2r, ao = lon * d2r;
        sortedA[pos]   = make_float4(sin_poly(al), cos_poly(al),
                                     sin_poly(ao), cos_poly(ao));
        sortedRaw[pos] = make_float2(lon, lat);
        sortedX[pos]   = x[i];
    }
}

// ---- main kernel (binned) ---------------------------------------------

__global__ __launch_bounds__(TPB) void gpr_binned(
    const float4* __restrict__ sortedA,   // (slat, clat, slon, clon)
    const float2* __restrict__ sortedRaw, // (lon, lat) raw degrees
    const float*  __restrict__ sortedX,
    const int*    __restrict__ cellStart, // [NCELLS+1]
    const float*  __restrict__ y_l,
    float* __restrict__ out, int ny, float Hcut, float HcutM)
{
    const int tid  = threadIdx.x;
    const int wave = tid >> 6;
    const int lane = tid & 63;
    const int y    = blockIdx.x * YPB + wave;

    const float d2r    = 0.017453292519943295f;
    const float r2d    = 57.29577951308232f;
    const float THRESH = 0.25f;
    const float DIAM   = 12.756f;
    const float DIAM6  = 12.756f / 6.0f;
    const float EPS_H  = 5e-8f;

    float lon_y = 0.0f, lat_y = 0.0f;
    if (y < ny) { lon_y = y_l[2 * y]; lat_y = y_l[2 * y + 1]; }
    const float sly   = sin_poly(lat_y * d2r);
    const float cly   = cos_poly(lat_y * d2r);
    const float slony = sin_poly(lon_y * d2r);
    const float clony = cos_poly(lon_y * d2r);

    float accw = 0.0f, accwx = 0.0f;

    const int s0 = max(0,          (int)floorf((lat_y - RLAT) * INV_CELL));
    const int s1 = min(NSTRIP - 1, (int)floorf((lat_y + RLAT) * INV_CELL));

    for (int s = s0; s <= s1; ++s) {
        // conservative min |dlat| from y to this strip
        float slo = s * C_CELL, shi = slo + C_CELL;
        float dmin = fmaxf(0.0f, fmaxf(slo - lat_y, lat_y - shi));
        float de   = fmaxf(0.0f, dmin - 3e-3f);
        float sd_  = sin_poly(de * d2r);
        float rem  = HcutM - sd_ * sd_;
        if (rem <= 0.0f) continue;
        // conservative min cos(lat_x)*cos(lat_y) over the strip
        float ccm = cos_poly(fminf(shi, 10.0f) * d2r) * cly * 0.999999f;
        float W   = asinf(fminf(1.0f, sqrtf(rem / ccm))) * r2d + 4e-3f;
        int lo = min(NLON - 1, max(0, (int)floorf((lon_y - W) * INV_CELL)));
        int hi = min(NLON - 1, max(0, (int)floorf((lon_y + W) * INV_CELL)));
        int p0 = cellStart[s * NLON + lo];
        int p1 = cellStart[s * NLON + hi + 1];

        for (int k = p0 + lane; k < p1; k += 64) {
            float4 e  = sortedA[k];
            float  xv = sortedX[k];

            float sl  = fmaf(e.x, cly,   -(e.y * sly));    // sin(dlat*d2r)
            float sd  = fmaf(e.z, clony, -(e.w * slony));  // sin(dlon*d2r)
            float cxy = e.y * cly;
            float hav = fmaf(sl, sl, cxy * (sd * sd));

            float tb  = hav - Hcut;
            float r   = __builtin_amdgcn_sqrtf(hav);
            float d   = r * fmaf(hav, DIAM6, DIAM);

            float w;
            if (__builtin_expect(fabsf(tb) < EPS_H, 0)) {
                // Emulate the numpy fp32 chain, every step correctly rounded.
                float2 raw = sortedRaw[k];
                float lonx = raw.x, latx = raw.y;

                float dlat = __fsub_rn(latx, lat_y);
                float alat = __fmul_rn(dlat, d2r);
                float slf  = (float)sin((double)alat);        // CR fp32 sin
                float h1   = __fmul_rn(slf, slf);

                float axl  = __fmul_rn(latx,  d2r);
                float ayl  = __fmul_rn(lat_y, d2r);
                float cxf  = (float)cos((double)axl);         // CR fp32 cos
                float cyf  = (float)cos((double)ayl);
                float cc   = __fmul_rn(cxf, cyf);

                float dlon = __fsub_rn(lonx, lon_y);
                float alon = __fmul_rn(dlon, d2r);
                float sdf  = (float)sin((double)alon);
                float h2   = __fmul_rn(sdf, sdf);

                float hv   = __fadd_rn(h1, __fmul_rn(cc, h2));
                float r32  = (float)sqrt((double)hv);         // CR fp32 sqrt
                float as32 = (float)asin((double)r32);        // CR fp32 asin
                float dnp  = __fmul_rn(DIAM, as32);
                w = (dnp < THRESH) ? dnp : 0.0f;
            } else {
                w = (tb < 0.0f) ? d : 0.0f;
            }

            accw += w;
            accwx = fmaf(w, xv, accwx);
        }
    }

    #pragma unroll
    for (int off = 32; off > 0; off >>= 1) {
        accw  += __shfl_xor(accw,  off, 64);
        accwx += __shfl_xor(accwx, off, 64);
    }

    if (lane == 0 && y < ny) {
        float m = (accw > 0.0f) ? (accwx / fmaxf(accw, 1e-12f)) : 0.0f;
        out[y]      = m;
        out[ny + y] = 0.001f;
    }
}

// ---- fallback: full scan (R3 structure), used if ws is too small ------

__global__ __launch_bounds__(TPB) void gpr_full(
    const float* __restrict__ x, const float* __restrict__ x_l,
    const float* __restrict__ y_l, float* __restrict__ out,
    int nx, int ny, float Hcut)
{
    __shared__ float4 tA[1024];
    __shared__ float  tX[1024];

    const int tid  = threadIdx.x;
    const int wave = tid >> 6;
    const int lane = tid & 63;
    const int y    = blockIdx.x * YPB + wave;

    const float d2r    = 0.017453292519943295f;
    const float THRESH = 0.25f;
    const float DIAM   = 12.756f;
    const float DIAM6  = 12.756f / 6.0f;
    const float EPS_H  = 5e-8f;

    float lon_y = 0.0f, lat_y = 0.0f;
    if (y < ny) { lon_y = y_l[2 * y]; lat_y = y_l[2 * y + 1]; }
    const float sly   = sin_poly(lat_y * d2r);
    const float cly   = cos_poly(lat_y * d2r);
    const float slony = sin_poly(lon_y * d2r);
    const float clony = cos_poly(lon_y * d2r);

    float accw = 0.0f, accwx = 0.0f;

    const int ntiles = (nx + 1023) / 1024;
    for (int t = 0; t < ntiles; ++t) {
        const int base = t * 1024;
        __syncthreads();
        #pragma unroll
        for (int j = 0; j < 1024 / TPB; ++j) {
            int idx = j * TPB + tid, i = base + idx;
            if (i < nx) {
                float lon = x_l[2 * i], lat = x_l[2 * i + 1];
                tA[idx] = make_float4(sin_poly(lat * d2r), cos_poly(lat * d2r),
                                      sin_poly(lon * d2r), cos_poly(lon * d2r));
                tX[idx] = x[i];
            }
        }
        __syncthreads();

        const int tn = min(1024, nx - base);
        for (int k = lane; k < tn; k += 64) {
            float4 e  = tA[k];
            float  xv = tX[k];
            float sl  = fmaf(e.x, cly,   -(e.y * sly));
            float sd  = fmaf(e.z, clony, -(e.w * slony));
            float cxy = e.y * cly;
            float hav = fmaf(sl, sl, cxy * (sd * sd));
            float tb  = hav - Hcut;
            float r   = __builtin_amdgcn_sqrtf(hav);
            float d   = r * fmaf(hav, DIAM6, DIAM);
            float w;
            if (__builtin_expect(fabsf(tb) < EPS_H, 0)) {
                int   i    = base + k;
                float lonx = x_l[2 * i], latx = x_l[2 * i + 1];
                float dlat = __fsub_rn(latx, lat_y);
                float alat = __fmul_rn(dlat, d2r);
                float slf  = (float)sin((double)alat);
                float h1   = __fmul_rn(slf, slf);
                float axl  = __fmul_rn(latx,  d2r);
                float ayl  = __fmul_rn(lat_y, d2r);
                float cxf  = (float)cos((double)axl);
                float cyf  = (float)cos((double)ayl);
                float cc   = __fmul_rn(cxf, cyf);
                float dlon = __fsub_rn(lonx, lon_y);
                float alon = __fmul_rn(dlon, d2r);
                float sdf  = (float)sin((double)alon);
                float h2   = __fmul_rn(sdf, sdf);
                float hv   = __fadd_rn(h1, __fmul_rn(cc, h2));
                float r32  = (float)sqrt((double)hv);
                float as32 = (float)asin((double)r32);
                float dnp  = __fmul_rn(DIAM, as32);
                w = (dnp < THRESH) ? dnp : 0.0f;
            } else {
                w = (tb < 0.0f) ? d : 0.0f;
            }
            accw += w;
            accwx = fmaf(w, xv, accwx);
        }
    }

    #pragma unroll
    for (int off = 32; off > 0; off >>= 1) {
        accw  += __shfl_xor(accw,  off, 64);
        accwx += __shfl_xor(accwx, off, 64);
    }

    if (lane == 0 && y < ny) {
        float m = (accw > 0.0f) ? (accwx / fmaxf(accw, 1e-12f)) : 0.0f;
        out[y]      = m;
        out[ny + y] = 0.001f;
    }
}

// ---- launcher ----------------------------------------------------------

extern "C" void kernel_launch(void* const* d_in, const int* in_sizes, int n_in,
                              void* d_out, int out_size, void* d_ws, size_t ws_size,
                              hipStream_t stream) {
    const float* x   = (const float*)d_in[0];
    const float* x_l = (const float*)d_in[1];
    const float* y_l = (const float*)d_in[2];
    float* out = (float*)d_out;

    const int nx = in_sizes[0];        // 20000
    const int ny = in_sizes[2] / 2;    // 6000

    // hav threshold, fp64 on host: sin^2(0.25/12.756)
    double th = 0.25 / 12.756;
    double s  = sin(th);
    float Hcut  = (float)(s * s);
    float HcutM = (float)(s * s * 1.001);   // margin for window pruning

    // ws layout (16B-aligned chunks)
    size_t offA   = 0;
    size_t offRaw = offA   + (size_t)nx * sizeof(float4);   // 16 nx
    size_t offX   = offRaw + (size_t)nx * sizeof(float2);   //  8 nx
    size_t offH   = offX   + (size_t)nx * sizeof(float);    //  4 nx
    size_t offCS  = offH   + (size_t)NCELLS * sizeof(int);
    size_t offCur = (offCS + (size_t)(NCELLS + 1) * sizeof(int) + 15) & ~(size_t)15;
    size_t total  = offCur + (size_t)NCELLS * sizeof(int);

    const int blocks = (ny + YPB - 1) / YPB;

    if (ws_size >= total) {
        float4* sortedA   = (float4*)((char*)d_ws + offA);
        float2* sortedRaw = (float2*)((char*)d_ws + offRaw);
        float*  sortedX   = (float*) ((char*)d_ws + offX);
        int*    hist      = (int*)   ((char*)d_ws + offH);
        int*    cellStart = (int*)   ((char*)d_ws + offCS);
        int*    cursor    = (int*)   ((char*)d_ws + offCur);

        int xb = (nx + TPB - 1) / TPB;
        zero_kernel<<<1, TPB, 0, stream>>>(hist);
        hist_kernel<<<xb, TPB, 0, stream>>>(x_l, hist, nx);
        scan_kernel<<<1, TPB, 0, stream>>>(hist, cellStart, cursor);
        scatter_kernel<<<xb, TPB, 0, stream>>>(x, x_l, cursor,
                                               sortedA, sortedRaw, sortedX, nx);
        gpr_binned<<<blocks, TPB, 0, stream>>>(sortedA, sortedRaw, sortedX,
                                               cellStart, y_l, out,
                                               ny, Hcut, HcutM);
    } else {
        gpr_full<<<blocks, TPB, 0, stream>>>(x, x_l, y_l, out, nx, ny, Hcut);
    }
}

// Round 7
// 91.371 us; speedup vs baseline: 2.6525x; 1.0259x over previous
//
#include <hip/hip_runtime.h>
#include <math.h>

// GPR_58746562675312: haversine-windowed weighted mean.
//   m[y] = sum_x w(y,x)*x[x] / sum_x w(y,x),  w = d if d<0.25 else 0,
//   d = 12.756 * asin(sqrt(hav(y,x)));  out = [m (ny), 0.001 (ny)]
//
// R7: R4-proven build pipeline (zero/hist/scan/scatter, global atomics)
// extended to also counting-sort the y points through the same 40x40 grid;
// main kernel processes y in sorted order (TPB=256, YPB=4, R4 shape) so
// co-scheduled waves share their x-window (L1-resident inner loads).
// The R5/R6 fused build kernel (suspect in container failures) is gone.
// Cutoff radius 1.123 deg (reference uses sin(D), not sin(D/2)).
// Boundary decisions: band +-5e-8 on hav -> CR fp32-chain emulation
// (byte-identical to the R2..R4 path that passed).

#define TPB    256
#define YPB    4      // y rows per block == waves per block (main kernel)
#define NSTRIP 40
#define NLON   40
#define NCELLS (NSTRIP * NLON)
#define C_CELL   0.25f
#define INV_CELL 4.0f
#define RLAT     1.1250f   // conservative window radius in degrees

__device__ __forceinline__ float sin_poly(float a) {
    float t = a * a;   // |a| <= 0.1746: err ~1e-9
    return a * fmaf(t, fmaf(t, 8.3333333e-3f, -0.16666667f), 1.0f);
}
__device__ __forceinline__ float cos_poly(float a) {
    float t = a * a;   // err ~2e-11
    return fmaf(t, fmaf(t, fmaf(t, -1.3888889e-3f, 4.1666668e-2f), -0.5f), 1.0f);
}
__device__ __forceinline__ int cell_of(float lon, float lat) {
    int s = (int)(lat * INV_CELL); s = min(max(s, 0), NSTRIP - 1);
    int l = (int)(lon * INV_CELL); l = min(max(l, 0), NLON - 1);
    return s * NLON + l;
}

// ---- binning pipeline (R4-proven shapes) ------------------------------

__global__ __launch_bounds__(TPB) void zero_kernel(int* __restrict__ histX,
                                                   int* __restrict__ histY) {
    for (int i = threadIdx.x; i < NCELLS; i += TPB) { histX[i] = 0; histY[i] = 0; }
}

__global__ __launch_bounds__(TPB) void hist_kernel(
    const float* __restrict__ x_l, const float* __restrict__ y_l,
    int* __restrict__ histX, int* __restrict__ histY, int nx, int ny)
{
    int i = blockIdx.x * TPB + threadIdx.x;
    if (i < nx) {
        atomicAdd(&histX[cell_of(x_l[2 * i], x_l[2 * i + 1])], 1);
    } else if (i < nx + ny) {
        int j = i - nx;
        atomicAdd(&histY[cell_of(y_l[2 * j], y_l[2 * j + 1])], 1);
    }
}

// grid = 2 blocks; block b scans hist[b] -> cellStart[b] (+total), cursor[b].
// Body identical to R4's proven single-block scan.
__global__ __launch_bounds__(TPB) void scan_kernel(
    const int* __restrict__ histX, const int* __restrict__ histY,
    int* __restrict__ csX, int* __restrict__ csY,
    int* __restrict__ curX, int* __restrict__ curY)
{
    const int CHUNK = (NCELLS + TPB - 1) / TPB;   // 7
    __shared__ int sums[TPB];
    const int* hist      = (blockIdx.x == 0) ? histX : histY;
    int*       cellStart = (blockIdx.x == 0) ? csX  : csY;
    int*       cursor    = (blockIdx.x == 0) ? curX : curY;

    int tid = threadIdx.x;
    int base = tid * CHUNK;
    int local[7];
    int s = 0;
    #pragma unroll
    for (int j = 0; j < CHUNK; ++j) {
        int idx = base + j;
        int v = (idx < NCELLS) ? hist[idx] : 0;
        local[j] = s; s += v;
    }
    sums[tid] = s;
    __syncthreads();
    for (int off = 1; off < TPB; off <<= 1) {
        int t = (tid >= off) ? sums[tid - off] : 0;
        __syncthreads();
        sums[tid] += t;
        __syncthreads();
    }
    int excl = (tid > 0) ? sums[tid - 1] : 0;
    #pragma unroll
    for (int j = 0; j < CHUNK; ++j) {
        int idx = base + j;
        if (idx < NCELLS) { cellStart[idx] = excl + local[j]; cursor[idx] = excl + local[j]; }
    }
    if (tid == TPB - 1) cellStart[NCELLS] = sums[TPB - 1];
}

__global__ __launch_bounds__(TPB) void scatter_kernel(
    const float* __restrict__ x, const float* __restrict__ x_l,
    const float* __restrict__ y_l,
    int* __restrict__ curX, int* __restrict__ curY,
    float4* __restrict__ sortedA, float2* __restrict__ sortedRaw,
    float*  __restrict__ sortedX,
    float2* __restrict__ sortedYL, int* __restrict__ sortedYIdx,
    int nx, int ny)
{
    const float d2r = 0.017453292519943295f;
    int i = blockIdx.x * TPB + threadIdx.x;
    if (i < nx) {
        float lon = x_l[2 * i], lat = x_l[2 * i + 1];
        int pos = atomicAdd(&curX[cell_of(lon, lat)], 1);
        float al = lat * d2r, ao = lon * d2r;
        sortedA[pos]   = make_float4(sin_poly(al), cos_poly(al),
                                     sin_poly(ao), cos_poly(ao));
        sortedRaw[pos] = make_float2(lon, lat);
        sortedX[pos]   = x[i];
    } else if (i < nx + ny) {
        int j = i - nx;
        float lon = y_l[2 * j], lat = y_l[2 * j + 1];
        int pos = atomicAdd(&curY[cell_of(lon, lat)], 1);
        sortedYL[pos]   = make_float2(lon, lat);
        sortedYIdx[pos] = j;
    }
}

// ---- main kernel (binned, y processed in sorted order) ----------------

__global__ __launch_bounds__(TPB) void gpr_binned(
    const float4* __restrict__ sortedA,   // (slat, clat, slon, clon)
    const float2* __restrict__ sortedRaw, // (lon, lat) raw degrees
    const float*  __restrict__ sortedX,
    const int*    __restrict__ cellStart, // [NCELLS+1] (x grid)
    const float2* __restrict__ sortedYL,
    const int*    __restrict__ sortedYIdx,
    float* __restrict__ out, int ny, float Hcut, float HcutM)
{
    const int tid  = threadIdx.x;
    const int wave = tid >> 6;
    const int lane = tid & 63;
    const int j    = blockIdx.x * YPB + wave;   // sorted-y position

    const float d2r    = 0.017453292519943295f;
    const float r2d    = 57.29577951308232f;
    const float THRESH = 0.25f;
    const float DIAM   = 12.756f;
    const float DIAM6  = 12.756f / 6.0f;
    const float EPS_H  = 5e-8f;

    int   yidx  = 0;
    float lon_y = 0.0f, lat_y = 0.0f;
    if (j < ny) {
        yidx = sortedYIdx[j];
        float2 p = sortedYL[j];
        lon_y = p.x; lat_y = p.y;
    }
    const float sly   = sin_poly(lat_y * d2r);
    const float cly   = cos_poly(lat_y * d2r);
    const float slony = sin_poly(lon_y * d2r);
    const float clony = cos_poly(lon_y * d2r);

    float accw = 0.0f, accwx = 0.0f;

    const int s0 = max(0,          (int)floorf((lat_y - RLAT) * INV_CELL));
    const int s1 = min(NSTRIP - 1, (int)floorf((lat_y + RLAT) * INV_CELL));

    for (int s = s0; s <= s1; ++s) {
        // conservative min |dlat| from y to this strip
        float slo = s * C_CELL, shi = slo + C_CELL;
        float dmin = fmaxf(0.0f, fmaxf(slo - lat_y, lat_y - shi));
        float de   = fmaxf(0.0f, dmin - 3e-3f);
        float sd_  = sin_poly(de * d2r);
        float rem  = HcutM - sd_ * sd_;
        if (rem <= 0.0f) continue;
        // conservative min cos(lat_x)*cos(lat_y) over the strip
        float ccm = cos_poly(fminf(shi, 10.0f) * d2r) * cly * 0.999999f;
        float W   = asinf(fminf(1.0f, sqrtf(rem / ccm))) * r2d + 4e-3f;
        int lo = min(NLON - 1, max(0, (int)floorf((lon_y - W) * INV_CELL)));
        int hi = min(NLON - 1, max(0, (int)floorf((lon_y + W) * INV_CELL)));
        int p0 = cellStart[s * NLON + lo];
        int p1 = cellStart[s * NLON + hi + 1];

        for (int k = p0 + lane; k < p1; k += 64) {
            float4 e  = sortedA[k];
            float  xv = sortedX[k];

            float sl  = fmaf(e.x, cly,   -(e.y * sly));    // sin(dlat*d2r)
            float sd  = fmaf(e.z, clony, -(e.w * slony));  // sin(dlon*d2r)
            float cxy = e.y * cly;
            float hav = fmaf(sl, sl, cxy * (sd * sd));

            float tb  = hav - Hcut;
            float r   = __builtin_amdgcn_sqrtf(hav);
            float d   = r * fmaf(hav, DIAM6, DIAM);

            float w;
            if (__builtin_expect(fabsf(tb) < EPS_H, 0)) {
                // Emulate the numpy fp32 chain, every step correctly rounded.
                float2 raw = sortedRaw[k];
                float lonx = raw.x, latx = raw.y;

                float dlat = __fsub_rn(latx, lat_y);
                float alat = __fmul_rn(dlat, d2r);
                float slf  = (float)sin((double)alat);        // CR fp32 sin
                float h1   = __fmul_rn(slf, slf);

                float axl  = __fmul_rn(latx,  d2r);
                float ayl  = __fmul_rn(lat_y, d2r);
                float cxf  = (float)cos((double)axl);         // CR fp32 cos
                float cyf  = (float)cos((double)ayl);
                float cc   = __fmul_rn(cxf, cyf);

                float dlon = __fsub_rn(lonx, lon_y);
                float alon = __fmul_rn(dlon, d2r);
                float sdf  = (float)sin((double)alon);
                float h2   = __fmul_rn(sdf, sdf);

                float hv   = __fadd_rn(h1, __fmul_rn(cc, h2));
                float r32  = (float)sqrt((double)hv);         // CR fp32 sqrt
                float as32 = (float)asin((double)r32);        // CR fp32 asin
                float dnp  = __fmul_rn(DIAM, as32);
                w = (dnp < THRESH) ? dnp : 0.0f;
            } else {
                w = (tb < 0.0f) ? d : 0.0f;
            }

            accw += w;
            accwx = fmaf(w, xv, accwx);
        }
    }

    #pragma unroll
    for (int off = 32; off > 0; off >>= 1) {
        accw  += __shfl_xor(accw,  off, 64);
        accwx += __shfl_xor(accwx, off, 64);
    }

    if (lane == 0 && j < ny) {
        float m = (accw > 0.0f) ? (accwx / fmaxf(accw, 1e-12f)) : 0.0f;
        out[yidx]      = m;
        out[ny + yidx] = 0.001f;
    }
}

// ---- fallback: full scan (R3 structure), used if ws is too small ------

__global__ __launch_bounds__(TPB) void gpr_full(
    const float* __restrict__ x, const float* __restrict__ x_l,
    const float* __restrict__ y_l, float* __restrict__ out,
    int nx, int ny, float Hcut)
{
    __shared__ float4 tA[1024];
    __shared__ float  tX[1024];

    const int tid  = threadIdx.x;
    const int wave = tid >> 6;
    const int lane = tid & 63;
    const int y    = blockIdx.x * YPB + wave;

    const float d2r    = 0.017453292519943295f;
    const float THRESH = 0.25f;
    const float DIAM   = 12.756f;
    const float DIAM6  = 12.756f / 6.0f;
    const float EPS_H  = 5e-8f;

    float lon_y = 0.0f, lat_y = 0.0f;
    if (y < ny) { lon_y = y_l[2 * y]; lat_y = y_l[2 * y + 1]; }
    const float sly   = sin_poly(lat_y * d2r);
    const float cly   = cos_poly(lat_y * d2r);
    const float slony = sin_poly(lon_y * d2r);
    const float clony = cos_poly(lon_y * d2r);

    float accw = 0.0f, accwx = 0.0f;

    const int ntiles = (nx + 1023) / 1024;
    for (int t = 0; t < ntiles; ++t) {
        const int base = t * 1024;
        __syncthreads();
        #pragma unroll
        for (int jj = 0; jj < 1024 / TPB; ++jj) {
            int idx = jj * TPB + tid, i = base + idx;
            if (i < nx) {
                float lon = x_l[2 * i], lat = x_l[2 * i + 1];
                tA[idx] = make_float4(sin_poly(lat * d2r), cos_poly(lat * d2r),
                                      sin_poly(lon * d2r), cos_poly(lon * d2r));
                tX[idx] = x[i];
            }
        }
        __syncthreads();

        const int tn = min(1024, nx - base);
        for (int k = lane; k < tn; k += 64) {
            float4 e  = tA[k];
            float  xv = tX[k];
            float sl  = fmaf(e.x, cly,   -(e.y * sly));
            float sd  = fmaf(e.z, clony, -(e.w * slony));
            float cxy = e.y * cly;
            float hav = fmaf(sl, sl, cxy * (sd * sd));
            float tb  = hav - Hcut;
            float r   = __builtin_amdgcn_sqrtf(hav);
            float d   = r * fmaf(hav, DIAM6, DIAM);
            float w;
            if (__builtin_expect(fabsf(tb) < EPS_H, 0)) {
                int   i    = base + k;
                float lonx = x_l[2 * i], latx = x_l[2 * i + 1];
                float dlat = __fsub_rn(latx, lat_y);
                float alat = __fmul_rn(dlat, d2r);
                float slf  = (float)sin((double)alat);
                float h1   = __fmul_rn(slf, slf);
                float axl  = __fmul_rn(latx,  d2r);
                float ayl  = __fmul_rn(lat_y, d2r);
                float cxf  = (float)cos((double)axl);
                float cyf  = (float)cos((double)ayl);
                float cc   = __fmul_rn(cxf, cyf);
                float dlon = __fsub_rn(lonx, lon_y);
                float alon = __fmul_rn(dlon, d2r);
                float sdf  = (float)sin((double)alon);
                float h2   = __fmul_rn(sdf, sdf);
                float hv   = __fadd_rn(h1, __fmul_rn(cc, h2));
                float r32  = (float)sqrt((double)hv);
                float as32 = (float)asin((double)r32);
                float dnp  = __fmul_rn(DIAM, as32);
                w = (dnp < THRESH) ? dnp : 0.0f;
            } else {
                w = (tb < 0.0f) ? d : 0.0f;
            }
            accw += w;
            accwx = fmaf(w, xv, accwx);
        }
    }

    #pragma unroll
    for (int off = 32; off > 0; off >>= 1) {
        accw  += __shfl_xor(accw,  off, 64);
        accwx += __shfl_xor(accwx, off, 64);
    }

    if (lane == 0 && y < ny) {
        float m = (accw > 0.0f) ? (accwx / fmaxf(accw, 1e-12f)) : 0.0f;
        out[y]      = m;
        out[ny + y] = 0.001f;
    }
}

// ---- launcher ----------------------------------------------------------

extern "C" void kernel_launch(void* const* d_in, const int* in_sizes, int n_in,
                              void* d_out, int out_size, void* d_ws, size_t ws_size,
                              hipStream_t stream) {
    const float* x   = (const float*)d_in[0];
    const float* x_l = (const float*)d_in[1];
    const float* y_l = (const float*)d_in[2];
    float* out = (float*)d_out;

    const int nx = in_sizes[0];        // 20000
    const int ny = in_sizes[2] / 2;    // 6000

    // hav threshold, fp64 on host: sin^2(0.25/12.756)
    double th = 0.25 / 12.756;
    double s  = sin(th);
    float Hcut  = (float)(s * s);
    float HcutM = (float)(s * s * 1.001);   // margin for window pruning

    // ws layout (16B-aligned start; 8/4-byte members naturally aligned)
    size_t offA   = 0;
    size_t offRaw = offA   + (size_t)nx * sizeof(float4);       // 16 nx
    size_t offYL  = offRaw + (size_t)nx * sizeof(float2);       //  8 nx
    size_t offX   = offYL  + (size_t)ny * sizeof(float2);       //  8 ny
    size_t offYI  = offX   + (size_t)nx * sizeof(float);        //  4 nx
    size_t offHX  = offYI  + (size_t)ny * sizeof(int);          //  4 ny
    size_t offHY  = offHX  + (size_t)NCELLS * sizeof(int);
    size_t offCSX = offHY  + (size_t)NCELLS * sizeof(int);
    size_t offCSY = offCSX + (size_t)(NCELLS + 1) * sizeof(int);
    size_t offCuX = offCSY + (size_t)(NCELLS + 1) * sizeof(int);
    size_t offCuY = offCuX + (size_t)NCELLS * sizeof(int);
    size_t total  = offCuY + (size_t)NCELLS * sizeof(int);

    const int blocks = (ny + YPB - 1) / YPB;

    if (ws_size >= total) {
        float4* sortedA    = (float4*)((char*)d_ws + offA);
        float2* sortedRaw  = (float2*)((char*)d_ws + offRaw);
        float2* sortedYL   = (float2*)((char*)d_ws + offYL);
        float*  sortedX    = (float*) ((char*)d_ws + offX);
        int*    sortedYIdx = (int*)   ((char*)d_ws + offYI);
        int*    histX      = (int*)   ((char*)d_ws + offHX);
        int*    histY      = (int*)   ((char*)d_ws + offHY);
        int*    csX        = (int*)   ((char*)d_ws + offCSX);
        int*    csY        = (int*)   ((char*)d_ws + offCSY);
        int*    curX       = (int*)   ((char*)d_ws + offCuX);
        int*    curY       = (int*)   ((char*)d_ws + offCuY);

        int nb = (nx + ny + TPB - 1) / TPB;
        zero_kernel<<<1, TPB, 0, stream>>>(histX, histY);
        hist_kernel<<<nb, TPB, 0, stream>>>(x_l, y_l, histX, histY, nx, ny);
        scan_kernel<<<2, TPB, 0, stream>>>(histX, histY, csX, csY, curX, curY);
        scatter_kernel<<<nb, TPB, 0, stream>>>(x, x_l, y_l, curX, curY,
                                               sortedA, sortedRaw, sortedX,
                                               sortedYL, sortedYIdx, nx, ny);
        gpr_binned<<<blocks, TPB, 0, stream>>>(sortedA, sortedRaw, sortedX,
                                               csX, sortedYL, sortedYIdx,
                                               out, ny, Hcut, HcutM);
    } else {
        gpr_full<<<blocks, TPB, 0, stream>>>(x, x_l, y_l, out, nx, ny, Hcut);
    }
}